// Round 2
// baseline (893.875 us; speedup 1.0000x reference)
//
#include <hip/hip_runtime.h>
#include <hip/hip_bf16.h>
#include <cfloat>
#include <math.h>

typedef __bf16 bf16;
typedef __bf16 bf16x4 __attribute__((ext_vector_type(4)));
typedef __bf16 bf16x8 __attribute__((ext_vector_type(8)));
typedef float  floatx4 __attribute__((ext_vector_type(4)));
typedef float  floatx2 __attribute__((ext_vector_type(2)));

#define SEQ 2048
#define DM  1024
#define NP  2048
#define CAP (1 << 20)
#define MARGIN 0.5f

// ---------------- mask dtype detect + expand to int[2048] ----------------
__global__ __launch_bounds__(256) void mask_prep(const void* __restrict__ mraw,
                                                 int* __restrict__ maskw) {
  __shared__ int flags;
  int t = threadIdx.x;
  if (t == 0) flags = 0;
  __syncthreads();
  const unsigned short* u16 = (const unsigned short*)mraw;
  const unsigned* u32 = (const unsigned*)mraw;
  int f = 0;
  for (int i = t; i < 1024; i += 256) {
    unsigned short v = u16[i];
    if (v != 0 && v != 0x3F80u) f |= 1;          // not bf16/fp32-looking
    if ((i & 1) == 0 && v == 0x3F80u) f |= 2;    // even u16 hit -> bf16 (not fp32)
  }
  for (int i = t; i < 512; i += 256)
    if (u32[i] > 1u) f |= 4;                     // not int32 0/1
  if (f) atomicOr(&flags, f);
  __syncthreads();
  int fl = flags;
  int mode;
  if (!(fl & 1)) mode = (fl & 2) ? 2 : 3;        // 2=bf16, 3=fp32
  else           mode = (fl & 4) ? 1 : 0;        // 1=uint8, 0=int32
  for (int s = t; s < SEQ; s += 256) {
    int m;
    if (mode == 0)      m = (((const int*)mraw)[s] != 0);
    else if (mode == 1) m = (((const unsigned char*)mraw)[s] != 0);
    else if (mode == 2) m = (u16[s] != 0);
    else                m = (((const float*)mraw)[s] != 0.0f);
    maskw[s] = m;
  }
}

// ---------------- Q/K projection, fp32 in, fp64 accumulate ----------------
// out layout head-major [16][2048][128]
__global__ __launch_bounds__(256) void proj_qk(
    const float* __restrict__ X,
    const float* __restrict__ Wq, const float* __restrict__ Wk,
    const float* __restrict__ bq, const float* __restrict__ bk,
    float* __restrict__ qo, float* __restrict__ ko) {
  const float* W   = blockIdx.z ? Wk : Wq;
  const float* bia = blockIdx.z ? bk : bq;
  float*       out = blockIdx.z ? ko : qo;
  __shared__ float Xs[32][68];   // [k][m]
  __shared__ float Ws[32][68];   // [k][n]
  int m0 = blockIdx.x * 64, n0 = blockIdx.y * 64;
  int t = threadIdx.x;
  int tm = (t & 15) * 4, tn = (t >> 4) * 4;
  int sr = t >> 3, sc = (t & 7) * 4;
  double acc[4][4] = {};
  for (int k0 = 0; k0 < DM; k0 += 32) {
    floatx4 xa = *(const floatx4*)(X + (size_t)(m0 + sr) * DM + k0 + sc);
    floatx4 xb = *(const floatx4*)(X + (size_t)(m0 + sr + 32) * DM + k0 + sc);
    floatx4 wa = *(const floatx4*)(W + (size_t)(k0 + sr) * NP + n0 + sc);
    floatx4 wb = *(const floatx4*)(W + (size_t)(k0 + sr) * NP + n0 + sc + 32);
    __syncthreads();
    for (int j = 0; j < 4; j++) { Xs[sc + j][sr] = xa[j]; Xs[sc + j][sr + 32] = xb[j]; }
    *(floatx4*)&Ws[sr][sc]      = wa;
    *(floatx4*)&Ws[sr][sc + 32] = wb;
    __syncthreads();
    for (int kk = 0; kk < 32; kk++) {
      floatx4 xv = *(const floatx4*)&Xs[kk][tm];
      floatx4 wv = *(const floatx4*)&Ws[kk][tn];
      double xd[4], wd[4];
      for (int i = 0; i < 4; i++) { xd[i] = (double)xv[i]; wd[i] = (double)wv[i]; }
      for (int i = 0; i < 4; i++)
        for (int j = 0; j < 4; j++)
          acc[i][j] = fma(xd[i], wd[j], acc[i][j]);
    }
  }
  for (int i = 0; i < 4; i++) {
    int m = m0 + tm + i;
    for (int j = 0; j < 4; j++) {
      int n = n0 + tn + j;
      float val = (float)(acc[i][j] + (double)bia[n]);
      out[((size_t)(n >> 7) * SEQ + m) * 128 + (n & 127)] = val;
    }
  }
}

// ---------------- V projection, fp32 acc, row-major out [2048][2048] -------
__global__ __launch_bounds__(256) void proj_v(
    const float* __restrict__ X, const float* __restrict__ W,
    const float* __restrict__ bia, float* __restrict__ out) {
  __shared__ float Xs[32][68];
  __shared__ float Ws[32][68];
  int m0 = blockIdx.x * 64, n0 = blockIdx.y * 64;
  int t = threadIdx.x;
  int tm = (t & 15) * 4, tn = (t >> 4) * 4;
  int sr = t >> 3, sc = (t & 7) * 4;
  float acc[4][4] = {};
  for (int k0 = 0; k0 < DM; k0 += 32) {
    floatx4 xa = *(const floatx4*)(X + (size_t)(m0 + sr) * DM + k0 + sc);
    floatx4 xb = *(const floatx4*)(X + (size_t)(m0 + sr + 32) * DM + k0 + sc);
    floatx4 wa = *(const floatx4*)(W + (size_t)(k0 + sr) * NP + n0 + sc);
    floatx4 wb = *(const floatx4*)(W + (size_t)(k0 + sr) * NP + n0 + sc + 32);
    __syncthreads();
    for (int j = 0; j < 4; j++) { Xs[sc + j][sr] = xa[j]; Xs[sc + j][sr + 32] = xb[j]; }
    *(floatx4*)&Ws[sr][sc]      = wa;
    *(floatx4*)&Ws[sr][sc + 32] = wb;
    __syncthreads();
    for (int kk = 0; kk < 32; kk++) {
      floatx4 xv = *(const floatx4*)&Xs[kk][tm];
      floatx4 wv = *(const floatx4*)&Ws[kk][tn];
      for (int i = 0; i < 4; i++)
        for (int j = 0; j < 4; j++)
          acc[i][j] = fmaf(xv[i], wv[j], acc[i][j]);
    }
  }
  for (int i = 0; i < 4; i++) {
    int m = m0 + tm + i;
    for (int j = 0; j < 4; j++) {
      int n = n0 + tn + j;
      out[(size_t)m * NP + n] = acc[i][j] + bia[n];
    }
  }
}

// ------- approx scores (bf16 MFMA), per-row masked min, candidate collect ---
__global__ __launch_bounds__(256) void scores_cand(
    const float* __restrict__ Q, const float* __restrict__ K,
    const int* __restrict__ mask,
    unsigned* __restrict__ cand, int* __restrict__ gcount) {
  int h = blockIdx.x, s0 = blockIdx.y * 64;
  __shared__ alignas(16) bf16 qs[64][136];
  __shared__ alignas(16) bf16 ks[64][136];
  __shared__ float lmin[64][65];
  __shared__ float fmin[64];
  __shared__ int   mt[64];
  int t = threadIdx.x;
  int w = t >> 6, lane = t & 63, l15 = lane & 15, qd = lane >> 4;
  const float* Qh = Q + (size_t)h * SEQ * 128;
  const float* Kh = K + (size_t)h * SEQ * 128;

  for (int jj = 0; jj < 8; jj++) {           // stage Q tile as bf16
    int idx = jj * 256 + t;
    int r = idx >> 5, c = (idx & 31) * 4;
    floatx4 v = *(const floatx4*)(Qh + (size_t)(s0 + r) * 128 + c);
    bf16x4 b; b[0] = (bf16)v[0]; b[1] = (bf16)v[1]; b[2] = (bf16)v[2]; b[3] = (bf16)v[3];
    *(bf16x4*)&qs[r][c] = b;
  }
  float rmin[4][4];
  for (int i = 0; i < 4; i++) for (int r = 0; r < 4; r++) rmin[i][r] = INFINITY;

  for (int phase = 0; phase < 2; phase++) {
    for (int tt = 0; tt < 32; tt++) {
      int t0 = tt * 64;
      __syncthreads();
      for (int jj = 0; jj < 8; jj++) {       // stage K tile as bf16
        int idx = jj * 256 + t;
        int r = idx >> 5, c = (idx & 31) * 4;
        floatx4 v = *(const floatx4*)(Kh + (size_t)(t0 + r) * 128 + c);
        bf16x4 b; b[0] = (bf16)v[0]; b[1] = (bf16)v[1]; b[2] = (bf16)v[2]; b[3] = (bf16)v[3];
        *(bf16x4*)&ks[r][c] = b;
      }
      if (t < 64) mt[t] = mask[t0 + t];
      __syncthreads();
      floatx4 acc[4];
      for (int i = 0; i < 4; i++) acc[i] = (floatx4){0.f, 0.f, 0.f, 0.f};
      for (int ksp = 0; ksp < 4; ksp++) {
        bf16x8 bfr = *(const bf16x8*)&ks[w * 16 + l15][ksp * 32 + qd * 8];
        for (int i = 0; i < 4; i++) {
          bf16x8 af = *(const bf16x8*)&qs[i * 16 + l15][ksp * 32 + qd * 8];
          acc[i] = __builtin_amdgcn_mfma_f32_16x16x32_bf16(af, bfr, acc[i], 0, 0, 0);
        }
      }
      int tg = t0 + w * 16 + l15;            // C/D: col=lane&15, row=qd*4+reg
      bool okc = mt[w * 16 + l15] != 0;
      if (phase == 0) {
        for (int i = 0; i < 4; i++)
          for (int r = 0; r < 4; r++)
            rmin[i][r] = fminf(rmin[i][r], okc ? acc[i][r] : INFINITY);
      } else {
        for (int i = 0; i < 4; i++)
          for (int r = 0; r < 4; r++) {
            int row = i * 16 + qd * 4 + r;
            if (okc && acc[i][r] <= fmin[row] && mask[s0 + row]) {
              int pos = atomicAdd(gcount, 1);
              if (pos < CAP)
                cand[pos] = ((unsigned)h << 22) | ((unsigned)(s0 + row) << 11) | (unsigned)tg;
            }
          }
      }
    }
    if (phase == 0) {
      for (int i = 0; i < 4; i++)
        for (int r = 0; r < 4; r++)
          lmin[i * 16 + qd * 4 + r][w * 16 + l15] = rmin[i][r];
      __syncthreads();
      if (t < 64) {
        float mv = INFINITY;
        for (int c = 0; c < 64; c++) mv = fminf(mv, lmin[t][c]);
        fmin[t] = mv + MARGIN;
      }
      __syncthreads();
    }
  }
}

// ---------------- fp64 exact rescore of candidates, atomicMin key ----------
__global__ __launch_bounds__(256) void rescore(
    const float* __restrict__ Q, const float* __restrict__ K,
    const unsigned* __restrict__ cand, const int* __restrict__ gcount,
    unsigned long long* __restrict__ keys) {
  int wid  = (blockIdx.x * 256 + threadIdx.x) >> 6;
  int lane = threadIdx.x & 63;
  int nw = gridDim.x * 4;
  int n = *gcount; if (n > CAP) n = CAP;
  for (int c = wid; c < n; c += nw) {
    unsigned u = cand[c];
    int h = u >> 22, s = (u >> 11) & 2047, tt = u & 2047;
    floatx2 qv = *(const floatx2*)(Q + ((size_t)h * SEQ + s)  * 128 + lane * 2);
    floatx2 kv = *(const floatx2*)(K + ((size_t)h * SEQ + tt) * 128 + lane * 2);
    double d = (double)qv[0] * (double)kv[0] + (double)qv[1] * (double)kv[1];
    for (int off = 32; off; off >>= 1) d += __shfl_down(d, off);
    if (lane == 0) {
      long long b = __double_as_longlong(d);
      unsigned long long ub = (b >= 0) ? ((unsigned long long)b | 0x8000000000000000ULL)
                                       : ~(unsigned long long)b;
      unsigned long long key = (ub & ~2047ULL) | (unsigned long long)tt;
      atomicMin(&keys[(size_t)h * SEQ + s], key);
    }
  }
}

// ---------------- column sums of V ----------------
__global__ __launch_bounds__(256) void vmean_partial(const float* __restrict__ V,
                                                     float* __restrict__ sums) {
  int n  = blockIdx.x * 256 + threadIdx.x;
  int s0 = blockIdx.y * 64;
  float s = 0.f;
  for (int r = 0; r < 64; r++) s += V[(size_t)(s0 + r) * NP + n];
  atomicAdd(&sums[n], s);
}

// ---------------- gather / mean, fp32 out ----------------
__global__ __launch_bounds__(256) void assemble(
    const float* __restrict__ V, const float* __restrict__ sums,
    const int* __restrict__ mask, const unsigned long long* __restrict__ keys,
    float* __restrict__ out) {
  int idx = blockIdx.x * 256 + threadIdx.x;
  int s = idx >> 11, n = idx & 2047, h = n >> 7;
  float val;
  if (mask[s]) {
    int tt = (int)(keys[(size_t)h * SEQ + s] & 2047ULL);
    val = V[(size_t)tt * NP + n];
  } else {
    val = sums[n] * (1.0f / 2048.0f);
  }
  out[idx] = val;
}

extern "C" void kernel_launch(void* const* d_in, const int* in_sizes, int n_in,
                              void* d_out, int out_size, void* d_ws, size_t ws_size,
                              hipStream_t stream) {
  (void)in_sizes; (void)n_in; (void)out_size; (void)ws_size;
  const float* X    = (const float*)d_in[0];
  const void*  mraw = d_in[1];
  const float* Wq   = (const float*)d_in[2];
  const float* bq   = (const float*)d_in[3];
  const float* Wk   = (const float*)d_in[4];
  const float* bk   = (const float*)d_in[5];
  const float* Wv   = (const float*)d_in[6];
  const float* bv   = (const float*)d_in[7];

  char* ws = (char*)d_ws;
  float* qf = (float*)ws;                                   // 16MB [16][2048][128]
  float* kf = (float*)(ws + ((size_t)16 << 20));            // 16MB
  float* vf = (float*)(ws + ((size_t)32 << 20));            // 16MB [2048][2048]
  int*   maskw  = (int*)(ws + ((size_t)48 << 20));                    // 8KB
  int*   gcount = (int*)(ws + ((size_t)48 << 20) + (16 << 10));       // 4B
  float* sums   = (float*)(ws + ((size_t)48 << 20) + (32 << 10));     // 8KB
  unsigned long long* keys = (unsigned long long*)(ws + ((size_t)48 << 20) + (64 << 10)); // 256KB
  unsigned* cand = (unsigned*)(ws + ((size_t)49 << 20));    // 4MB
  float* out = (float*)d_out;

  mask_prep<<<1, 256, 0, stream>>>(mraw, maskw);
  hipMemsetAsync(gcount, 0, 4, stream);
  hipMemsetAsync(sums, 0, 2048 * sizeof(float), stream);
  hipMemsetAsync(keys, 0xFF, (size_t)16 * SEQ * 8, stream);
  proj_qk<<<dim3(32, 32, 2), 256, 0, stream>>>(X, Wq, Wk, bq, bk, qf, kf);
  proj_v<<<dim3(32, 32), 256, 0, stream>>>(X, Wv, bv, vf);
  scores_cand<<<dim3(16, 32), 256, 0, stream>>>(qf, kf, maskw, cand, gcount);
  rescore<<<1024, 256, 0, stream>>>(qf, kf, cand, gcount, keys);
  vmean_partial<<<dim3(8, 32), 256, 0, stream>>>(vf, sums);
  assemble<<<16384, 256, 0, stream>>>(vf, sums, maskw, keys, out);
}

// Round 4
// 844.515 us; speedup vs baseline: 1.0584x; 1.0584x over previous
//
#include <hip/hip_runtime.h>
#include <hip/hip_bf16.h>
#include <cfloat>
#include <math.h>

typedef __bf16 bf16;
typedef __bf16 bf16x4 __attribute__((ext_vector_type(4)));
typedef __bf16 bf16x8 __attribute__((ext_vector_type(8)));
typedef float  floatx4 __attribute__((ext_vector_type(4)));
typedef float  floatx2 __attribute__((ext_vector_type(2)));

#define SEQ 2048
#define DM  1024
#define NP  2048
#define CAP (1 << 20)
#define MARGIN 0.5f

// ---------------- mask dtype detect + expand to int[2048] ----------------
__global__ __launch_bounds__(256) void mask_prep(const void* __restrict__ mraw,
                                                 int* __restrict__ maskw) {
  __shared__ int flags;
  int t = threadIdx.x;
  if (t == 0) flags = 0;
  __syncthreads();
  const unsigned short* u16 = (const unsigned short*)mraw;
  const unsigned* u32 = (const unsigned*)mraw;
  int f = 0;
  for (int i = t; i < 1024; i += 256) {
    unsigned short v = u16[i];
    if (v != 0 && v != 0x3F80u) f |= 1;
    if ((i & 1) == 0 && v == 0x3F80u) f |= 2;
  }
  for (int i = t; i < 512; i += 256)
    if (u32[i] > 1u) f |= 4;
  if (f) atomicOr(&flags, f);
  __syncthreads();
  int fl = flags;
  int mode;
  if (!(fl & 1)) mode = (fl & 2) ? 2 : 3;
  else           mode = (fl & 4) ? 1 : 0;
  for (int s = t; s < SEQ; s += 256) {
    int m;
    if (mode == 0)      m = (((const int*)mraw)[s] != 0);
    else if (mode == 1) m = (((const unsigned char*)mraw)[s] != 0);
    else if (mode == 2) m = (u16[s] != 0);
    else                m = (((const float*)mraw)[s] != 0.0f);
    maskw[s] = m;
  }
}

// ---------------- Q/K projection, fp64 VALU, 8x8 register blocking ----------
// Numerics: identical fp64 FMA chain (ascending k) to the round-2 PASS.
// 128x128 tile, BK=16. A in LDS [k][m] (broadcast reads), B in LDS [n][k].
__global__ __launch_bounds__(256, 2) void proj_qk(
    const float* __restrict__ X,
    const float* __restrict__ Wq, const float* __restrict__ Wk,
    const float* __restrict__ bq, const float* __restrict__ bk,
    float* __restrict__ qo, float* __restrict__ ko) {
  int z = blockIdx.z;
  const float* W   = z ? Wk : Wq;
  const float* bia = z ? bk : bq;
  float*       out = z ? ko : qo;
  __shared__ double Xs[16][136];   // [k][m]
  __shared__ double Ws[128][17];   // [n][k]
  int m0 = blockIdx.x * 128, n0 = blockIdx.y * 128;
  int t = threadIdx.x;
  int g  = t >> 4;        // m-group: m = g + 16*i
  int tn = t & 15;        // n-lane:  n = tn + 16*j  (coalesced stores)
  int ar = t >> 1, ac = (t & 1) * 8;    // A staging: 128m x 16k
  int br = t >> 4, bc = (t & 15) * 8;   // B staging: 16k x 128n
  double acc[8][8];
  for (int i = 0; i < 8; i++)
    for (int j = 0; j < 8; j++) acc[i][j] = 0.0;

  for (int kt = 0; kt < DM; kt += 16) {
    floatx4 xa0 = *(const floatx4*)(X + (size_t)(m0 + ar) * DM + kt + ac);
    floatx4 xa1 = *(const floatx4*)(X + (size_t)(m0 + ar) * DM + kt + ac + 4);
    floatx4 wv0 = *(const floatx4*)(W + (size_t)(kt + br) * NP + n0 + bc);
    floatx4 wv1 = *(const floatx4*)(W + (size_t)(kt + br) * NP + n0 + bc + 4);
    __syncthreads();
    for (int j = 0; j < 4; j++) {
      Xs[ac + j][ar]     = (double)xa0[j];
      Xs[ac + 4 + j][ar] = (double)xa1[j];
      Ws[bc + j][br]     = (double)wv0[j];
      Ws[bc + 4 + j][br] = (double)wv1[j];
    }
    __syncthreads();
    #pragma unroll 2
    for (int kk = 0; kk < 16; kk++) {
      double av[8], bv[8];
      for (int i = 0; i < 8; i++) av[i] = Xs[kk][g + 16 * i];
      for (int j = 0; j < 8; j++) bv[j] = Ws[tn + 16 * j][kk];
      for (int i = 0; i < 8; i++)
        for (int j = 0; j < 8; j++)
          acc[i][j] = fma(av[i], bv[j], acc[i][j]);
    }
  }
  int head = n0 >> 7;   // block spans exactly one head in n
  for (int j = 0; j < 8; j++) {
    int col = tn + 16 * j;
    double bb = (double)bia[n0 + col];
    for (int i = 0; i < 8; i++) {
      int m = m0 + g + 16 * i;
      out[((size_t)head * SEQ + m) * 128 + col] = (float)(acc[i][j] + bb);
    }
  }
}

// ---------------- V projection via bf16 MFMA, out row-major [2048][2048] ----
__global__ __launch_bounds__(256) void proj_v_mfma(
    const float* __restrict__ X, const float* __restrict__ W,
    const float* __restrict__ bia, float* __restrict__ out) {
  __shared__ alignas(16) bf16 As[128][40];  // [m][k] BK=32
  __shared__ alignas(16) bf16 Bs[128][40];  // [n][k]
  int ms = blockIdx.x * 128, ns = blockIdx.y * 128;
  int t = threadIdx.x, w = t >> 6, lane = t & 63, l15 = lane & 15, qd = lane >> 4;
  int wm = (w >> 1) * 64, wn = (w & 1) * 64;
  int amr = t >> 1, akb = (t & 1) * 16;
  int bkr = t >> 3, bnb = (t & 7) * 16;
  floatx4 acc[4][4];
  for (int i = 0; i < 4; i++)
    for (int j = 0; j < 4; j++) acc[i][j] = (floatx4){0.f, 0.f, 0.f, 0.f};

  for (int kt = 0; kt < DM; kt += 32) {
    floatx4 xa[4], wv[4];
    for (int u = 0; u < 4; u++)
      xa[u] = *(const floatx4*)(X + (size_t)(ms + amr) * DM + kt + akb + u * 4);
    for (int u = 0; u < 4; u++)
      wv[u] = *(const floatx4*)(W + (size_t)(kt + bkr) * NP + ns + bnb + u * 4);
    __syncthreads();
    {
      bf16x8 p0, p1;
      for (int j = 0; j < 4; j++) { p0[j] = (bf16)xa[0][j]; p0[4 + j] = (bf16)xa[1][j]; }
      for (int j = 0; j < 4; j++) { p1[j] = (bf16)xa[2][j]; p1[4 + j] = (bf16)xa[3][j]; }
      *(bf16x8*)&As[amr][akb]     = p0;
      *(bf16x8*)&As[amr][akb + 8] = p1;
    }
    for (int u = 0; u < 4; u++)
      for (int j = 0; j < 4; j++)
        Bs[bnb + u * 4 + j][bkr] = (bf16)wv[u][j];
    __syncthreads();
    bf16x8 af[4], bfr[4];
    for (int i = 0; i < 4; i++) af[i]  = *(const bf16x8*)&As[wm + i * 16 + l15][qd * 8];
    for (int j = 0; j < 4; j++) bfr[j] = *(const bf16x8*)&Bs[wn + j * 16 + l15][qd * 8];
    for (int i = 0; i < 4; i++)
      for (int j = 0; j < 4; j++)
        acc[i][j] = __builtin_amdgcn_mfma_f32_16x16x32_bf16(af[i], bfr[j], acc[i][j], 0, 0, 0);
  }
  for (int i = 0; i < 4; i++) {
    for (int j = 0; j < 4; j++) {
      int n = ns + wn + j * 16 + l15;
      float bb = bia[n];
      for (int r = 0; r < 4; r++) {
        int m = ms + wm + i * 16 + qd * 4 + r;
        out[(size_t)m * NP + n] = acc[i][j][r] + bb;
      }
    }
  }
}

// ------- approx scores (bf16 MFMA), per-row masked min, candidate collect ---
// Verbatim from the round-2 PASS.
__global__ __launch_bounds__(256) void scores_cand(
    const float* __restrict__ Q, const float* __restrict__ K,
    const int* __restrict__ mask,
    unsigned* __restrict__ cand, int* __restrict__ gcount) {
  int h = blockIdx.x, s0 = blockIdx.y * 64;
  __shared__ alignas(16) bf16 qs[64][136];
  __shared__ alignas(16) bf16 ks[64][136];
  __shared__ float lmin[64][65];
  __shared__ float fmin[64];
  __shared__ int   mt[64];
  int t = threadIdx.x;
  int w = t >> 6, lane = t & 63, l15 = lane & 15, qd = lane >> 4;
  const float* Qh = Q + (size_t)h * SEQ * 128;
  const float* Kh = K + (size_t)h * SEQ * 128;

  for (int jj = 0; jj < 8; jj++) {
    int idx = jj * 256 + t;
    int r = idx >> 5, c = (idx & 31) * 4;
    floatx4 v = *(const floatx4*)(Qh + (size_t)(s0 + r) * 128 + c);
    bf16x4 b; b[0] = (bf16)v[0]; b[1] = (bf16)v[1]; b[2] = (bf16)v[2]; b[3] = (bf16)v[3];
    *(bf16x4*)&qs[r][c] = b;
  }
  float rmin[4][4];
  for (int i = 0; i < 4; i++) for (int r = 0; r < 4; r++) rmin[i][r] = INFINITY;

  for (int phase = 0; phase < 2; phase++) {
    for (int tt = 0; tt < 32; tt++) {
      int t0 = tt * 64;
      __syncthreads();
      for (int jj = 0; jj < 8; jj++) {
        int idx = jj * 256 + t;
        int r = idx >> 5, c = (idx & 31) * 4;
        floatx4 v = *(const floatx4*)(Kh + (size_t)(t0 + r) * 128 + c);
        bf16x4 b; b[0] = (bf16)v[0]; b[1] = (bf16)v[1]; b[2] = (bf16)v[2]; b[3] = (bf16)v[3];
        *(bf16x4*)&ks[r][c] = b;
      }
      if (t < 64) mt[t] = mask[t0 + t];
      __syncthreads();
      floatx4 acc[4];
      for (int i = 0; i < 4; i++) acc[i] = (floatx4){0.f, 0.f, 0.f, 0.f};
      for (int ksp = 0; ksp < 4; ksp++) {
        bf16x8 bfr = *(const bf16x8*)&ks[w * 16 + l15][ksp * 32 + qd * 8];
        for (int i = 0; i < 4; i++) {
          bf16x8 af = *(const bf16x8*)&qs[i * 16 + l15][ksp * 32 + qd * 8];
          acc[i] = __builtin_amdgcn_mfma_f32_16x16x32_bf16(af, bfr, acc[i], 0, 0, 0);
        }
      }
      int tg = t0 + w * 16 + l15;
      bool okc = mt[w * 16 + l15] != 0;
      if (phase == 0) {
        for (int i = 0; i < 4; i++)
          for (int r = 0; r < 4; r++)
            rmin[i][r] = fminf(rmin[i][r], okc ? acc[i][r] : INFINITY);
      } else {
        for (int i = 0; i < 4; i++)
          for (int r = 0; r < 4; r++) {
            int row = i * 16 + qd * 4 + r;
            if (okc && acc[i][r] <= fmin[row] && mask[s0 + row]) {
              int pos = atomicAdd(gcount, 1);
              if (pos < CAP)
                cand[pos] = ((unsigned)h << 22) | ((unsigned)(s0 + row) << 11) | (unsigned)tg;
            }
          }
      }
    }
    if (phase == 0) {
      for (int i = 0; i < 4; i++)
        for (int r = 0; r < 4; r++)
          lmin[i * 16 + qd * 4 + r][w * 16 + l15] = rmin[i][r];
      __syncthreads();
      if (t < 64) {
        float mv = INFINITY;
        for (int c = 0; c < 64; c++) mv = fminf(mv, lmin[t][c]);
        fmin[t] = mv + MARGIN;
      }
      __syncthreads();
    }
  }
}

// ---------------- fp64 exact rescore of candidates, atomicMin key ----------
__global__ __launch_bounds__(256) void rescore(
    const float* __restrict__ Q, const float* __restrict__ K,
    const unsigned* __restrict__ cand, const int* __restrict__ gcount,
    unsigned long long* __restrict__ keys) {
  int wid  = (blockIdx.x * 256 + threadIdx.x) >> 6;
  int lane = threadIdx.x & 63;
  int nw = gridDim.x * 4;
  int n = *gcount; if (n > CAP) n = CAP;
  for (int c = wid; c < n; c += nw) {
    unsigned u = cand[c];
    int h = u >> 22, s = (u >> 11) & 2047, tt = u & 2047;
    floatx2 qv = *(const floatx2*)(Q + ((size_t)h * SEQ + s)  * 128 + lane * 2);
    floatx2 kv = *(const floatx2*)(K + ((size_t)h * SEQ + tt) * 128 + lane * 2);
    double d = (double)qv[0] * (double)kv[0] + (double)qv[1] * (double)kv[1];
    for (int off = 32; off; off >>= 1) d += __shfl_down(d, off);
    if (lane == 0) {
      long long b = __double_as_longlong(d);
      unsigned long long ub = (b >= 0) ? ((unsigned long long)b | 0x8000000000000000ULL)
                                       : ~(unsigned long long)b;
      unsigned long long key = (ub & ~2047ULL) | (unsigned long long)tt;
      atomicMin(&keys[(size_t)h * SEQ + s], key);
    }
  }
}

// ---------------- column sums of V ----------------
__global__ __launch_bounds__(256) void vmean_partial(const float* __restrict__ V,
                                                     float* __restrict__ sums) {
  int n  = blockIdx.x * 256 + threadIdx.x;
  int s0 = blockIdx.y * 64;
  float s = 0.f;
  for (int r = 0; r < 64; r++) s += V[(size_t)(s0 + r) * NP + n];
  atomicAdd(&sums[n], s);
}

// ---------------- gather / mean, fp32 out ----------------
__global__ __launch_bounds__(256) void assemble(
    const float* __restrict__ V, const float* __restrict__ sums,
    const int* __restrict__ mask, const unsigned long long* __restrict__ keys,
    float* __restrict__ out) {
  int idx = blockIdx.x * 256 + threadIdx.x;
  int s = idx >> 11, n = idx & 2047, h = n >> 7;
  float val;
  if (mask[s]) {
    int tt = (int)(keys[(size_t)h * SEQ + s] & 2047ULL);
    val = V[(size_t)tt * NP + n];
  } else {
    val = sums[n] * (1.0f / 2048.0f);
  }
  out[idx] = val;
}

extern "C" void kernel_launch(void* const* d_in, const int* in_sizes, int n_in,
                              void* d_out, int out_size, void* d_ws, size_t ws_size,
                              hipStream_t stream) {
  (void)in_sizes; (void)n_in; (void)out_size; (void)ws_size;
  const float* X    = (const float*)d_in[0];
  const void*  mraw = d_in[1];
  const float* Wq   = (const float*)d_in[2];
  const float* bq   = (const float*)d_in[3];
  const float* Wk   = (const float*)d_in[4];
  const float* bk   = (const float*)d_in[5];
  const float* Wv   = (const float*)d_in[6];
  const float* bv   = (const float*)d_in[7];

  char* ws = (char*)d_ws;
  float* qf = (float*)ws;                                   // 16MB [16][2048][128]
  float* kf = (float*)(ws + ((size_t)16 << 20));            // 16MB
  float* vf = (float*)(ws + ((size_t)32 << 20));            // 16MB [2048][2048]
  int*   maskw  = (int*)(ws + ((size_t)48 << 20));                    // 8KB
  int*   gcount = (int*)(ws + ((size_t)48 << 20) + (16 << 10));       // 4B
  float* sums   = (float*)(ws + ((size_t)48 << 20) + (32 << 10));     // 8KB
  unsigned long long* keys = (unsigned long long*)(ws + ((size_t)48 << 20) + (64 << 10)); // 256KB
  unsigned* cand = (unsigned*)(ws + ((size_t)49 << 20));    // 4MB
  float* out = (float*)d_out;

  mask_prep<<<1, 256, 0, stream>>>(mraw, maskw);
  hipMemsetAsync(gcount, 0, 4, stream);
  hipMemsetAsync(sums, 0, 2048 * sizeof(float), stream);
  hipMemsetAsync(keys, 0xFF, (size_t)16 * SEQ * 8, stream);
  proj_qk<<<dim3(16, 16, 2), 256, 0, stream>>>(X, Wq, Wk, bq, bk, qf, kf);
  proj_v_mfma<<<dim3(16, 16), 256, 0, stream>>>(X, Wv, bv, vf);
  scores_cand<<<dim3(16, 32), 256, 0, stream>>>(qf, kf, maskw, cand, gcount);
  rescore<<<1024, 256, 0, stream>>>(qf, kf, cand, gcount, keys);
  vmean_partial<<<dim3(8, 32), 256, 0, stream>>>(vf, sums);
  assemble<<<16384, 256, 0, stream>>>(vf, sums, maskw, keys, out);
}